// Round 10
// baseline (355.498 us; speedup 1.0000x reference)
//
#include <hip/hip_runtime.h>
#include <hip/hip_bf16.h>

#define N_NODES 50000
#define N_PER   12500
#define E_EDGES 600000
#define HDIM    128

#define NBLK_BUILD ((E_EDGES + 255) / 256)        // 2344
#define NBLK_FC    ((N_PER + 63) / 64)            // 196

typedef __attribute__((ext_vector_type(8))) short bfrag;   // 8 bf16 (4 VGPRs)
typedef __attribute__((ext_vector_type(4))) float ffrag;   // 4 fp32 acc

__device__ __forceinline__ unsigned short f2bf(float f) {
    union { float f; unsigned u; } x; x.f = f;
    unsigned r = x.u + 0x7fffu + ((x.u >> 16) & 1u);   // RTNE
    return (unsigned short)(r >> 16);
}
__device__ __forceinline__ float lo_bf(unsigned v) { return __uint_as_float(v << 16); }
__device__ __forceinline__ float hi_bf(unsigned v) { return __uint_as_float(v & 0xffff0000u); }
__device__ __forceinline__ unsigned pack2(float a, float b) {
    return (unsigned)f2bf(a) | ((unsigned)f2bf(b) << 16);
}
__device__ __forceinline__ float onrm_of(int deg) {
    return rsqrtf(fmaxf((float)deg, 1.0f));
}

__device__ __forceinline__ void acc8_add(float* acc, uint4 v) {
    acc[0] += lo_bf(v.x); acc[1] += hi_bf(v.x);
    acc[2] += lo_bf(v.y); acc[3] += hi_bf(v.y);
    acc[4] += lo_bf(v.z); acc[5] += hi_bf(v.z);
    acc[6] += lo_bf(v.w); acc[7] += hi_bf(v.w);
}
__device__ __forceinline__ void acc8_addw(float* acc, uint4 v, float w) {
    acc[0] += lo_bf(v.x) * w; acc[1] += hi_bf(v.x) * w;
    acc[2] += lo_bf(v.y) * w; acc[3] += hi_bf(v.y) * w;
    acc[4] += lo_bf(v.z) * w; acc[5] += hi_bf(v.z) * w;
    acc[6] += lo_bf(v.w) * w; acc[7] += hi_bf(v.w) * w;
}

// ---------------------------------------------------------------------------
// K0: weight fragment packing (blocks 0..31) + init (blocks 32..).
//   init ints: head_in[N]=-1, head_b[N]=-1, deg_out[N]=0, cursors[64]=0.
// ---------------------------------------------------------------------------
__global__ __launch_bounds__(256) void prep_kernel(
    const float* __restrict__ W0, const float* __restrict__ W1,
    const float* __restrict__ W2, const float* __restrict__ W3,
    const float* __restrict__ Wg,
    unsigned short* __restrict__ Wp, int* __restrict__ initp) {
    int b = blockIdx.x;
    if (b < 32) {
        int tid = b * 256 + threadIdx.x;
        const float* W; int D, base, off;
        if      (tid < 2048) { W = W0; D = 128; base = 0;    off = 0;     }
        else if (tid < 4096) { W = W1; D = 128; base = 2048; off = 16384; }
        else if (tid < 5120) { W = W2; D = 64;  base = 4096; off = 32768; }
        else if (tid < 6144) { W = W3; D = 64;  base = 5120; off = 40960; }
        else                 { W = Wg; D = 128; base = 6144; off = 49152; }
        int t2 = tid - base;
        int KT = D / 32;
        int l = t2 & 63;
        int tt = t2 >> 6;
        int kt = tt % KT, n0 = tt / KT;
        int n = n0 * 16 + (l & 15);
        int kb = kt * 32 + (l >> 4) * 8;
#pragma unroll
        for (int j = 0; j < 8; ++j)
            Wp[(size_t)off + (size_t)t2 * 8 + j] = f2bf(W[(size_t)(kb + j) * 128 + n]);
    } else {
        int blk = b - 32;
#pragma unroll
        for (int k = 0; k < 4; ++k) {
            int i = blk * 1024 + k * 256 + threadIdx.x;
            if (i < 3 * N_NODES + 64)
                initp[i] = (i < 2 * N_NODES) ? -1 : 0;
        }
    }
}

// ---------------------------------------------------------------------------
// FC MFMA body: out = bf16(X(rows x D) @ W + bias); X fp32.
// ---------------------------------------------------------------------------
template<int D>
__device__ __forceinline__ void fc_body(
    int blk, int tid,
    const float* __restrict__ X,
    const unsigned short* __restrict__ Wp,
    const float* __restrict__ bias,
    unsigned short* __restrict__ outbf,
    int rows)
{
    constexpr int KT = D / 32;
    const int lane = tid & 63;
    const int wave = tid >> 6;
    const int m = lane & 15, q = lane >> 4;
    const int rbase = blk * 64 + wave * 16;
    const int row = rbase + m;

    bfrag afr[KT];
#pragma unroll
    for (int kt = 0; kt < KT; ++kt) {
        bfrag a;
        if (row < rows) {
            const float* xp = X + (size_t)row * D + kt * 32 + q * 8;
            float4 u0 = *(const float4*)xp;
            float4 u1 = *(const float4*)(xp + 4);
            a[0] = (short)f2bf(u0.x); a[1] = (short)f2bf(u0.y);
            a[2] = (short)f2bf(u0.z); a[3] = (short)f2bf(u0.w);
            a[4] = (short)f2bf(u1.x); a[5] = (short)f2bf(u1.y);
            a[6] = (short)f2bf(u1.z); a[7] = (short)f2bf(u1.w);
        } else {
#pragma unroll
            for (int t = 0; t < 8; ++t) a[t] = 0;
        }
        afr[kt] = a;
    }

    ffrag acc[8];
#pragma unroll
    for (int n0 = 0; n0 < 8; ++n0)
#pragma unroll
        for (int t = 0; t < 4; ++t) acc[n0][t] = 0.f;

#pragma unroll
    for (int n0 = 0; n0 < 8; ++n0)
#pragma unroll
        for (int kt = 0; kt < KT; ++kt) {
            bfrag bfr = *(const bfrag*)(Wp + ((size_t)(n0 * KT + kt) * 64 + lane) * 8);
            acc[n0] = __builtin_amdgcn_mfma_f32_16x16x32_bf16(afr[kt], bfr, acc[n0], 0, 0, 0);
        }

#pragma unroll
    for (int n0 = 0; n0 < 8; ++n0) {
        const int col = n0 * 16 + m;
        const float bj = bias[col];
#pragma unroll
        for (int r = 0; r < 4; ++r) {
            int orow = rbase + q * 4 + r;
            if (orow < rows)
                outbf[(size_t)orow * 128 + col] = f2bf(acc[n0][r] + bj);
        }
    }
}

// ---------------------------------------------------------------------------
// K1 mega-kernel: build chains (atomic-bound) + 4 FC GEMMs (MFMA-bound).
// ---------------------------------------------------------------------------
__global__ __launch_bounds__(256) void mega_kernel(
    const int* __restrict__ src, const int* __restrict__ dst,
    const int* __restrict__ ef,
    int* __restrict__ head_in, int* __restrict__ head_b,
    int* __restrict__ deg_out,
    int2* __restrict__ edge2, int2* __restrict__ bwd2,
    const float* __restrict__ f0, const float* __restrict__ f1,
    const float* __restrict__ f2, const float* __restrict__ f3,
    const unsigned short* __restrict__ Wp,
    const float* __restrict__ b0, const float* __restrict__ b1,
    const float* __restrict__ b2, const float* __restrict__ b3,
    unsigned short* __restrict__ Abf)
{
    const int b = blockIdx.x;
    if (b < NBLK_BUILD) {
        int e = b * 256 + threadIdx.x;
        if (e >= E_EDGES) return;
        int s = src[e], d = dst[e], t = ef[e];
        int nx = atomicExch(&head_in[d], e);
        edge2[e] = make_int2(s | ((t <= 4) ? 0x80000000 : 0), nx);
        atomicAdd(&deg_out[s], 1);
        if (t == 6 || t == 14 || t == 30) {
            int nb = atomicExch(&head_b[s], e);
            bwd2[e] = make_int2(d, nb);
        }
    } else {
        int fb = b - NBLK_BUILD;
        int which = fb / NBLK_FC;
        int blk = fb - which * NBLK_FC;
        if (which == 0)
            fc_body<128>(blk, threadIdx.x, f0, Wp,         b0, Abf + (size_t)0 * N_PER * HDIM, N_PER);
        else if (which == 1)
            fc_body<128>(blk, threadIdx.x, f1, Wp + 16384, b1, Abf + (size_t)1 * N_PER * HDIM, N_PER);
        else if (which == 2)
            fc_body<64>(blk, threadIdx.x, f2, Wp + 32768, b2, Abf + (size_t)2 * N_PER * HDIM, N_PER);
        else
            fc_body<64>(blk, threadIdx.x, f3, Wp + 40960, b3, Abf + (size_t)3 * N_PER * HDIM, N_PER);
    }
}

// ---------------------------------------------------------------------------
// K2: flatten chains -> flat lists (the ONLY pointer-chase) + A-scale.
//   16-lane groups share one chain walk (broadcast loads); lane j8 captures
//   iterations i%16==j8; block-aggregated cursor alloc; coalesced writes.
//   Then the block scales its 16 A rows by onrm(deg_out[row]) — deletes
//   agg0's 600k random per-edge deg loads. Grid is exactly 3125 blocks.
// ---------------------------------------------------------------------------
__global__ __launch_bounds__(256) void flatten_kernel(
    const int* __restrict__ head, const int2* __restrict__ edge2,
    const int* __restrict__ headb, const int2* __restrict__ bwd2,
    const int* __restrict__ deg_out,
    int* __restrict__ cursors,
    int* __restrict__ flat, int* __restrict__ flatB,
    int* __restrict__ base_arr, int* __restrict__ cnt_arr,
    int* __restrict__ baseB_arr, int* __restrict__ cntB_arr,
    uint4* __restrict__ A) {
    __shared__ int lcnt[16], lcntB[16], lbase[16], lbaseB[16];
    int idx = blockIdx.x * blockDim.x + threadIdx.x;
    int n = idx >> 4;                   // always < N_NODES (exact grid)
    int j8 = idx & 15;
    int ln = threadIdx.x >> 4;

    // fwd chain walk + capture
    int k0 = 0, k1 = 0, k2 = 0, k3 = 0;
    int cnt = 0;
    int e = head[n];
    while (e >= 0) {
        int2 pn = edge2[e];
        if ((cnt & 15) == j8) {
            int ki = cnt >> 4;
            if      (ki == 0) k0 = pn.x;
            else if (ki == 1) k1 = pn.x;
            else if (ki == 2) k2 = pn.x;
            else if (ki == 3) k3 = pn.x;
        }
        ++cnt;
        e = pn.y;
    }
    // bwd chain walk + capture
    int kb0 = 0, kb1 = 0;
    int cntB = 0;
    e = headb[n];
    while (e >= 0) {
        int2 pn = bwd2[e];
        if ((cntB & 15) == j8) {
            int ki = cntB >> 4;
            if      (ki == 0) kb0 = pn.x;
            else if (ki == 1) kb1 = pn.x;
        }
        ++cntB;
        e = pn.y;
    }

    // block-aggregated flat-slot allocation (one atomic per cursor per block)
    if (j8 == 0) { lcnt[ln] = cnt; lcntB[ln] = cntB; }
    __syncthreads();
    if (threadIdx.x == 0) {
        int sa = 0, sb = 0;
#pragma unroll
        for (int i = 0; i < 16; ++i) {
            lbase[i] = sa;  sa += lcnt[i];
            lbaseB[i] = sb; sb += lcntB[i];
        }
        int ba = atomicAdd(&cursors[0], sa);
        int bb = atomicAdd(&cursors[1], sb);
#pragma unroll
        for (int i = 0; i < 16; ++i) { lbase[i] += ba; lbaseB[i] += bb; }
    }
    __syncthreads();
    const int base = lbase[ln], baseB = lbaseB[ln];

    if (0 * 16 + j8 < cnt) flat[base + 0 * 16 + j8] = k0;
    if (1 * 16 + j8 < cnt) flat[base + 1 * 16 + j8] = k1;
    if (2 * 16 + j8 < cnt) flat[base + 2 * 16 + j8] = k2;
    if (3 * 16 + j8 < cnt) flat[base + 3 * 16 + j8] = k3;
    if (0 * 16 + j8 < cntB) flatB[baseB + 0 * 16 + j8] = kb0;
    if (1 * 16 + j8 < cntB) flatB[baseB + 1 * 16 + j8] = kb1;

    // overflow fallbacks (not taken at this degree distribution)
    if (cnt > 64 && j8 == 0) {
        int e2 = head[n]; int i = 0;
        while (e2 >= 0) { int2 pn = edge2[e2]; if (i >= 64) flat[base + i] = pn.x; ++i; e2 = pn.y; }
    }
    if (cntB > 32 && j8 == 0) {
        int e2 = headb[n]; int i = 0;
        while (e2 >= 0) { int2 pn = bwd2[e2]; if (i >= 32) flatB[baseB + i] = pn.x; ++i; e2 = pn.y; }
    }

    if (j8 == 0) {
        base_arr[n] = base;   cnt_arr[n] = cnt;
        baseB_arr[n] = baseB; cntB_arr[n] = cntB;
    }

    // A-scale: A[n] *= onrm(deg_out[n]) — coalesced 256 B/row, bf16 round-trip
    float on = onrm_of(deg_out[n]);
    uint4 v = A[(size_t)n * 16 + j8];
    uint4 o;
    o.x = pack2(lo_bf(v.x) * on, hi_bf(v.x) * on);
    o.y = pack2(lo_bf(v.y) * on, hi_bf(v.y) * on);
    o.z = pack2(lo_bf(v.z) * on, hi_bf(v.z) * on);
    o.w = pack2(lo_bf(v.w) * on, hi_bf(v.w) * on);
    A[(size_t)n * 16 + j8] = o;
}

// ---------------------------------------------------------------------------
// K3: layer-0 gather — CLEAN flat gather (A pre-scaled by onrm).
//   B[n] = bf16( relu( (sum A[s]) * inrm(n) + b_g0 ) * onrm(n) )
// ---------------------------------------------------------------------------
__global__ __launch_bounds__(256) void agg0_kernel(
    const uint4* __restrict__ A,
    const int* __restrict__ flat,
    const int* __restrict__ base_arr, const int* __restrict__ cnt_arr,
    const int* __restrict__ deg_out, const float* __restrict__ b_g0,
    uint4* __restrict__ B) {
    int idx = blockIdx.x * blockDim.x + threadIdx.x;
    int n = idx >> 4;
    if (n >= N_NODES) return;
    int j8 = idx & 15;
    const int base = base_arr[n], cnt = cnt_arr[n];
    float acc[8] = {0.f, 0.f, 0.f, 0.f, 0.f, 0.f, 0.f, 0.f};
    for (int i = 0; i < cnt; ++i) {
        int s = flat[base + i] & 0x7fffffff;
        acc8_add(acc, A[(size_t)s * 16 + j8]);
    }
    float inr = onrm_of(cnt);
    float onr = onrm_of(deg_out[n]);
    const float* bg = b_g0 + j8 * 8;
    float r[8];
#pragma unroll
    for (int k = 0; k < 8; ++k)
        r[k] = fmaxf(acc[k] * inr + bg[k], 0.f) * onr;
    uint4 o;
    o.x = pack2(r[0], r[1]); o.y = pack2(r[2], r[3]);
    o.z = pack2(r[4], r[5]); o.w = pack2(r[6], r[7]);
    B[(size_t)n * 16 + j8] = o;
}

// ---------------------------------------------------------------------------
// K4: fused layer-1 gather (flat list) + MFMA GEMM.
// ---------------------------------------------------------------------------
__global__ __launch_bounds__(256) void gemm1_fused_kernel(
    const unsigned short* __restrict__ Bbf,
    const int* __restrict__ flat,
    const int* __restrict__ base_arr, const int* __restrict__ cnt_arr,
    const unsigned short* __restrict__ Wp, const float* __restrict__ bias,
    unsigned short* __restrict__ outbf)
{
    const int lane = threadIdx.x & 63;
    const int wave = threadIdx.x >> 6;
    const int m = lane & 15, q = lane >> 4;
    const int rbase = blockIdx.x * 64 + wave * 16;
    const int node = rbase + m;

    float ga[32];
#pragma unroll
    for (int i = 0; i < 32; ++i) ga[i] = 0.f;

    int mycnt = 0;
    if (node < N_NODES) {
        const int base = base_arr[node];
        mycnt = cnt_arr[node];
        for (int i = 0; i < mycnt; ++i) {
            int s = flat[base + i] & 0x7fffffff;
            const uint4* rp = (const uint4*)(Bbf + (size_t)s * 128);
#pragma unroll
            for (int kt = 0; kt < 4; ++kt) {
                uint4 v = rp[kt * 4 + q];
                ga[kt * 8 + 0] += lo_bf(v.x); ga[kt * 8 + 1] += hi_bf(v.x);
                ga[kt * 8 + 2] += lo_bf(v.y); ga[kt * 8 + 3] += hi_bf(v.y);
                ga[kt * 8 + 4] += lo_bf(v.z); ga[kt * 8 + 5] += hi_bf(v.z);
                ga[kt * 8 + 6] += lo_bf(v.w); ga[kt * 8 + 7] += hi_bf(v.w);
            }
        }
    }

    bfrag afr[4];
#pragma unroll
    for (int kt = 0; kt < 4; ++kt)
#pragma unroll
        for (int j = 0; j < 8; ++j)
            afr[kt][j] = (short)f2bf(ga[kt * 8 + j]);

    ffrag acc[8];
#pragma unroll
    for (int n0 = 0; n0 < 8; ++n0)
#pragma unroll
        for (int t = 0; t < 4; ++t) acc[n0][t] = 0.f;

#pragma unroll
    for (int n0 = 0; n0 < 8; ++n0)
#pragma unroll
        for (int kt = 0; kt < 4; ++kt) {
            bfrag bfr = *(const bfrag*)(Wp + ((size_t)(n0 * 4 + kt) * 64 + lane) * 8);
            acc[n0] = __builtin_amdgcn_mfma_f32_16x16x32_bf16(afr[kt], bfr, acc[n0], 0, 0, 0);
        }

    // inrm for output rows (rows rbase+q*4+r): from cnt via shuffle-free reload
    float ir[4];
#pragma unroll
    for (int r = 0; r < 4; ++r) {
        int orow = rbase + q * 4 + r;
        ir[r] = (orow < N_NODES) ? onrm_of(cnt_arr[orow]) : 0.f;
    }
#pragma unroll
    for (int n0 = 0; n0 < 8; ++n0) {
        const int col = n0 * 16 + m;
        const float bj = bias[col];
#pragma unroll
        for (int r = 0; r < 4; ++r) {
            int orow = rbase + q * 4 + r;
            if (orow < N_NODES)
                outbf[(size_t)orow * 128 + col] = f2bf(fmaxf(acc[n0][r] * ir[r] + bj, 0.f));
        }
    }
}

// ---------------------------------------------------------------------------
// K5: final edge-typed gather (flat lists) -> fp32 out.
// ---------------------------------------------------------------------------
__global__ __launch_bounds__(256) void final_kernel(
    const uint4* __restrict__ H,
    const int* __restrict__ flat,
    const int* __restrict__ base_arr, const int* __restrict__ cnt_arr,
    const int* __restrict__ flatB,
    const int* __restrict__ baseB_arr, const int* __restrict__ cntB_arr,
    float4* __restrict__ out4) {
    int idx = blockIdx.x * blockDim.x + threadIdx.x;
    int n = idx >> 4;
    if (n >= N_NODES) return;
    int j8 = idx & 15;
    float acc[8] = {0.f, 0.f, 0.f, 0.f, 0.f, 0.f, 0.f, 0.f};
    const int base = base_arr[n], cnt = cnt_arr[n];
    for (int i = 0; i < cnt; ++i) {
        int c = flat[base + i];
        int s = c & 0x7fffffff;
        float w = (c < 0) ? 2.0f : 1.0f;
        acc8_addw(acc, H[(size_t)s * 16 + j8], w);
    }
    const int baseB = baseB_arr[n], cntB = cntB_arr[n];
    for (int i = 0; i < cntB; ++i) {
        int d = flatB[baseB + i];
        acc8_add(acc, H[(size_t)d * 16 + j8]);
    }
    float4 o0 = {acc[0], acc[1], acc[2], acc[3]};
    float4 o1 = {acc[4], acc[5], acc[6], acc[7]};
    out4[(size_t)n * 32 + j8 * 2]     = o0;
    out4[(size_t)n * 32 + j8 * 2 + 1] = o1;
}

extern "C" void kernel_launch(void* const* d_in, const int* in_sizes, int n_in,
                              void* d_out, int out_size, void* d_ws, size_t ws_size,
                              hipStream_t stream) {
    const float* feat[4]  = {(const float*)d_in[0], (const float*)d_in[3],
                             (const float*)d_in[6], (const float*)d_in[9]};
    const float* W_fc[4]  = {(const float*)d_in[1], (const float*)d_in[4],
                             (const float*)d_in[7], (const float*)d_in[10]};
    const float* b_fc[4]  = {(const float*)d_in[2], (const float*)d_in[5],
                             (const float*)d_in[8], (const float*)d_in[11]};
    const int*   src      = (const int*)d_in[12];
    const int*   dst      = (const int*)d_in[13];
    const int*   efeat    = (const int*)d_in[14];
    const float* b_g0     = (const float*)d_in[15];
    const float* W_g1     = (const float*)d_in[16];
    const float* b_g1     = (const float*)d_in[17];
    float* out = (float*)d_out;

    // ---- workspace layout (16B blocks first), ~46 MB ----
    char* p = (char*)d_ws;
    unsigned short* Abf = (unsigned short*)p; p += (size_t)N_NODES * HDIM * 2;  // 12.8 MB
    unsigned short* Bbf = (unsigned short*)p; p += (size_t)N_NODES * HDIM * 2;  // 12.8 MB
    unsigned short* Wp  = (unsigned short*)p; p += (size_t)65536 * 2;           // 128 KB
    int2* edge2  = (int2*)p; p += (size_t)E_EDGES * 8;   // 4.8 MB
    int2* bwd2   = (int2*)p; p += (size_t)E_EDGES * 8;   // 4.8 MB
    int* flat    = (int*)p; p += (size_t)E_EDGES * 4;    // 2.4 MB
    int* flatB   = (int*)p; p += (size_t)E_EDGES * 4;    // 2.4 MB
    // init region: head_in | head_b | deg_out | cursors (contiguous)
    int* head_in = (int*)p; p += (size_t)N_NODES * 4;
    int* head_b  = (int*)p; p += (size_t)N_NODES * 4;
    int* deg_out = (int*)p; p += (size_t)N_NODES * 4;
    int* cursors = (int*)p; p += 64 * 4;
    int* base_arr  = (int*)p; p += (size_t)N_NODES * 4;
    int* cnt_arr   = (int*)p; p += (size_t)N_NODES * 4;
    int* baseB_arr = (int*)p; p += (size_t)N_NODES * 4;
    int* cntB_arr  = (int*)p; p += (size_t)N_NODES * 4;

    const unsigned short* Wpg = Wp + 49152;

    // K0: weight packing + init (heads=-1, deg=0, cursors=0)
    prep_kernel<<<32 + (3 * N_NODES + 64 + 1023) / 1024, 256, 0, stream>>>(
        W_fc[0], W_fc[1], W_fc[2], W_fc[3], W_g1, Wp, head_in);

    // K1: fused graph build (atomics) + 4 FC GEMMs (MFMA)
    mega_kernel<<<NBLK_BUILD + 4 * NBLK_FC, 256, 0, stream>>>(
        src, dst, efeat, head_in, head_b, deg_out, edge2, bwd2,
        feat[0], feat[1], feat[2], feat[3], Wp,
        b_fc[0], b_fc[1], b_fc[2], b_fc[3], Abf);

    const int grid_node = (N_NODES * 16 + 255) / 256;   // 3125 exact

    // K2: flatten chains (only pointer-chase) + A *= onrm
    flatten_kernel<<<grid_node, 256, 0, stream>>>(
        head_in, edge2, head_b, bwd2, deg_out, cursors,
        flat, flatB, base_arr, cnt_arr, baseB_arr, cntB_arr,
        (uint4*)Abf);

    // K3: layer0 clean flat gather
    agg0_kernel<<<grid_node, 256, 0, stream>>>(
        (const uint4*)Abf, flat, base_arr, cnt_arr, deg_out, b_g0,
        (uint4*)Bbf);

    // K4: fused layer1 gather (flat) + GEMM
    gemm1_fused_kernel<<<(N_NODES + 63) / 64, 256, 0, stream>>>(
        Bbf, flat, base_arr, cnt_arr, Wpg, b_g1, Abf);

    // K5: final edge-typed gather (flat) into fp32 d_out
    final_kernel<<<grid_node, 256, 0, stream>>>(
        (const uint4*)Abf, flat, base_arr, cnt_arr,
        flatB, baseB_arr, cntB_arr, (float4*)out);
}

// Round 11
// 273.438 us; speedup vs baseline: 1.3001x; 1.3001x over previous
//
#include <hip/hip_runtime.h>
#include <hip/hip_bf16.h>

#define N_NODES 50000
#define N_PER   12500
#define E_EDGES 600000
#define HDIM    128

#define NBLK_BUILD ((E_EDGES + 255) / 256)        // 2344
#define NBLK_FC    ((N_PER + 63) / 64)            // 196
#define BK_CAP  32     // fwd bucket slots/node; P(Poisson(12) > 32) ~ 1e-6
#define BKB_CAP 8      // bwd bucket slots/node; P(Poisson(1) > 8) ~ 1e-6
#define MASK31  0x7fffffff

typedef __attribute__((ext_vector_type(8))) short bfrag;   // 8 bf16 (4 VGPRs)
typedef __attribute__((ext_vector_type(4))) float ffrag;   // 4 fp32 acc

__device__ __forceinline__ unsigned short f2bf(float f) {
    union { float f; unsigned u; } x; x.f = f;
    unsigned r = x.u + 0x7fffu + ((x.u >> 16) & 1u);   // RTNE
    return (unsigned short)(r >> 16);
}
__device__ __forceinline__ float lo_bf(unsigned v) { return __uint_as_float(v << 16); }
__device__ __forceinline__ float hi_bf(unsigned v) { return __uint_as_float(v & 0xffff0000u); }
__device__ __forceinline__ unsigned pack2(float a, float b) {
    return (unsigned)f2bf(a) | ((unsigned)f2bf(b) << 16);
}
__device__ __forceinline__ float onrm_of(int deg) {
    return rsqrtf(fmaxf((float)deg, 1.0f));
}

__device__ __forceinline__ void acc8_add(float* acc, uint4 v) {
    acc[0] += lo_bf(v.x); acc[1] += hi_bf(v.x);
    acc[2] += lo_bf(v.y); acc[3] += hi_bf(v.y);
    acc[4] += lo_bf(v.z); acc[5] += hi_bf(v.z);
    acc[6] += lo_bf(v.w); acc[7] += hi_bf(v.w);
}
__device__ __forceinline__ void acc8_addw(float* acc, uint4 v, float w) {
    acc[0] += lo_bf(v.x) * w; acc[1] += hi_bf(v.x) * w;
    acc[2] += lo_bf(v.y) * w; acc[3] += hi_bf(v.y) * w;
    acc[4] += lo_bf(v.z) * w; acc[5] += hi_bf(v.z) * w;
    acc[6] += lo_bf(v.w) * w; acc[7] += hi_bf(v.w) * w;
}

// ---------------------------------------------------------------------------
// K0: weight fragment packing (blocks 0..31) + init (blocks 32..276).
//   init ints (contiguous, 250k): head_ov[50k]=-1, head_ovB[50k]=-1,
//   cnt_in[50k]=0, cntB[50k]=0, deg_out[50k]=0.
// ---------------------------------------------------------------------------
__global__ __launch_bounds__(256) void prep_kernel(
    const float* __restrict__ W0, const float* __restrict__ W1,
    const float* __restrict__ W2, const float* __restrict__ W3,
    const float* __restrict__ Wg,
    unsigned short* __restrict__ Wp, int* __restrict__ initp) {
    int b = blockIdx.x;
    if (b < 32) {
        int tid = b * 256 + threadIdx.x;
        const float* W; int D, base, off;
        if      (tid < 2048) { W = W0; D = 128; base = 0;    off = 0;     }
        else if (tid < 4096) { W = W1; D = 128; base = 2048; off = 16384; }
        else if (tid < 5120) { W = W2; D = 64;  base = 4096; off = 32768; }
        else if (tid < 6144) { W = W3; D = 64;  base = 5120; off = 40960; }
        else                 { W = Wg; D = 128; base = 6144; off = 49152; }
        int t2 = tid - base;
        int KT = D / 32;
        int l = t2 & 63;
        int tt = t2 >> 6;
        int kt = tt % KT, n0 = tt / KT;
        int n = n0 * 16 + (l & 15);
        int kb = kt * 32 + (l >> 4) * 8;
#pragma unroll
        for (int j = 0; j < 8; ++j)
            Wp[(size_t)off + (size_t)t2 * 8 + j] = f2bf(W[(size_t)(kb + j) * 128 + n]);
    } else {
        int blk = b - 32;
#pragma unroll
        for (int k = 0; k < 4; ++k) {
            int i = blk * 1024 + k * 256 + threadIdx.x;
            if (i < 5 * N_NODES)
                initp[i] = (i < 2 * N_NODES) ? -1 : 0;
        }
    }
}

// ---------------------------------------------------------------------------
// FC MFMA body: out = bf16(X(rows x D) @ W + bias); X fp32.
// ---------------------------------------------------------------------------
template<int D>
__device__ __forceinline__ void fc_body(
    int blk, int tid,
    const float* __restrict__ X,
    const unsigned short* __restrict__ Wp,
    const float* __restrict__ bias,
    unsigned short* __restrict__ outbf,
    int rows)
{
    constexpr int KT = D / 32;
    const int lane = tid & 63;
    const int wave = tid >> 6;
    const int m = lane & 15, q = lane >> 4;
    const int rbase = blk * 64 + wave * 16;
    const int row = rbase + m;

    bfrag afr[KT];
#pragma unroll
    for (int kt = 0; kt < KT; ++kt) {
        bfrag a;
        if (row < rows) {
            const float* xp = X + (size_t)row * D + kt * 32 + q * 8;
            float4 u0 = *(const float4*)xp;
            float4 u1 = *(const float4*)(xp + 4);
            a[0] = (short)f2bf(u0.x); a[1] = (short)f2bf(u0.y);
            a[2] = (short)f2bf(u0.z); a[3] = (short)f2bf(u0.w);
            a[4] = (short)f2bf(u1.x); a[5] = (short)f2bf(u1.y);
            a[6] = (short)f2bf(u1.z); a[7] = (short)f2bf(u1.w);
        } else {
#pragma unroll
            for (int t = 0; t < 8; ++t) a[t] = 0;
        }
        afr[kt] = a;
    }

    ffrag acc[8];
#pragma unroll
    for (int n0 = 0; n0 < 8; ++n0)
#pragma unroll
        for (int t = 0; t < 4; ++t) acc[n0][t] = 0.f;

#pragma unroll
    for (int n0 = 0; n0 < 8; ++n0)
#pragma unroll
        for (int kt = 0; kt < KT; ++kt) {
            bfrag bfr = *(const bfrag*)(Wp + ((size_t)(n0 * KT + kt) * 64 + lane) * 8);
            acc[n0] = __builtin_amdgcn_mfma_f32_16x16x32_bf16(afr[kt], bfr, acc[n0], 0, 0, 0);
        }

#pragma unroll
    for (int n0 = 0; n0 < 8; ++n0) {
        const int col = n0 * 16 + m;
        const float bj = bias[col];
#pragma unroll
        for (int r = 0; r < 4; ++r) {
            int orow = rbase + q * 4 + r;
            if (orow < rows)
                outbf[(size_t)orow * 128 + col] = f2bf(acc[n0][r] + bj);
        }
    }
}

// ---------------------------------------------------------------------------
// K1 mega-kernel: bucket build (atomic-bound) + 4 FC GEMMs (MFMA-bound).
//   Each edge goes directly into bucket[d*32 + p] (p from returning
//   atomicAdd); p>=32 -> rare overflow chain. No pointer-chase downstream.
// ---------------------------------------------------------------------------
__global__ __launch_bounds__(256) void mega_kernel(
    const int* __restrict__ src, const int* __restrict__ dst,
    const int* __restrict__ ef,
    int* __restrict__ cnt_in, int* __restrict__ cntB,
    int* __restrict__ deg_out,
    int* __restrict__ bucket, int* __restrict__ bucketB,
    int* __restrict__ head_ov, int* __restrict__ ov_pay, int* __restrict__ ov_nxt,
    int* __restrict__ head_ovB, int* __restrict__ ovB_pay, int* __restrict__ ovB_nxt,
    const float* __restrict__ f0, const float* __restrict__ f1,
    const float* __restrict__ f2, const float* __restrict__ f3,
    const unsigned short* __restrict__ Wp,
    const float* __restrict__ b0, const float* __restrict__ b1,
    const float* __restrict__ b2, const float* __restrict__ b3,
    unsigned short* __restrict__ Abf)
{
    const int b = blockIdx.x;
    if (b < NBLK_BUILD) {
        int e = b * 256 + threadIdx.x;
        if (e >= E_EDGES) return;
        int s = src[e], d = dst[e], t = ef[e];
        int v = s | ((t <= 4) ? 0x80000000 : 0);   // bit31: fwd weight == 2
        int p = atomicAdd(&cnt_in[d], 1);
        if (p < BK_CAP) bucket[d * BK_CAP + p] = v;
        else { ov_pay[e] = v; ov_nxt[e] = atomicExch(&head_ov[d], e); }
        atomicAdd(&deg_out[s], 1);
        if (t == 6 || t == 14 || t == 30) {
            int p2 = atomicAdd(&cntB[s], 1);
            if (p2 < BKB_CAP) bucketB[s * BKB_CAP + p2] = d;
            else { ovB_pay[e] = d; ovB_nxt[e] = atomicExch(&head_ovB[s], e); }
        }
    } else {
        int fb = b - NBLK_BUILD;
        int which = fb / NBLK_FC;
        int blk = fb - which * NBLK_FC;
        if (which == 0)
            fc_body<128>(blk, threadIdx.x, f0, Wp,         b0, Abf + (size_t)0 * N_PER * HDIM, N_PER);
        else if (which == 1)
            fc_body<128>(blk, threadIdx.x, f1, Wp + 16384, b1, Abf + (size_t)1 * N_PER * HDIM, N_PER);
        else if (which == 2)
            fc_body<64>(blk, threadIdx.x, f2, Wp + 32768, b2, Abf + (size_t)2 * N_PER * HDIM, N_PER);
        else
            fc_body<64>(blk, threadIdx.x, f3, Wp + 40960, b3, Abf + (size_t)3 * N_PER * HDIM, N_PER);
    }
}

// ---------------------------------------------------------------------------
// K2: A[n] *= onrm(deg_out[n]) — coalesced; deletes agg0's 600k random
//   per-edge deg loads. Grid exactly 3125 blocks.
// ---------------------------------------------------------------------------
__global__ __launch_bounds__(256) void scale_kernel(
    uint4* __restrict__ A, const int* __restrict__ deg_out) {
    int idx = blockIdx.x * blockDim.x + threadIdx.x;
    int n = idx >> 4, j8 = idx & 15;
    float on = onrm_of(deg_out[n]);
    uint4 v = A[(size_t)n * 16 + j8];
    uint4 o;
    o.x = pack2(lo_bf(v.x) * on, hi_bf(v.x) * on);
    o.y = pack2(lo_bf(v.y) * on, hi_bf(v.y) * on);
    o.z = pack2(lo_bf(v.z) * on, hi_bf(v.z) * on);
    o.w = pack2(lo_bf(v.w) * on, hi_bf(v.w) * on);
    A[(size_t)n * 16 + j8] = o;
}

// ---------------------------------------------------------------------------
// K3: layer-0 gather from bucket (A pre-scaled), unroll-4 for MLP.
//   B[n] = bf16( relu( (sum A[s]) * inrm(n) + b_g0 ) * onrm(n) )
// ---------------------------------------------------------------------------
__global__ __launch_bounds__(256) void agg0_kernel(
    const uint4* __restrict__ A,
    const int* __restrict__ bucket, const int* __restrict__ cnt_in,
    const int* __restrict__ head_ov, const int* __restrict__ ov_pay,
    const int* __restrict__ ov_nxt,
    const int* __restrict__ deg_out, const float* __restrict__ b_g0,
    uint4* __restrict__ B) {
    int idx = blockIdx.x * blockDim.x + threadIdx.x;
    int n = idx >> 4, j8 = idx & 15;
    const int cnt = cnt_in[n];
    const int* bk = bucket + (size_t)n * BK_CAP;
    float acc[8] = {0.f, 0.f, 0.f, 0.f, 0.f, 0.f, 0.f, 0.f};
    int lim = min(cnt, BK_CAP);
    int i = 0;
    for (; i + 4 <= lim; i += 4) {
        int s0 = bk[i] & MASK31,     s1 = bk[i + 1] & MASK31;
        int s2 = bk[i + 2] & MASK31, s3 = bk[i + 3] & MASK31;
        uint4 v0 = A[(size_t)s0 * 16 + j8];
        uint4 v1 = A[(size_t)s1 * 16 + j8];
        uint4 v2 = A[(size_t)s2 * 16 + j8];
        uint4 v3 = A[(size_t)s3 * 16 + j8];
        acc8_add(acc, v0); acc8_add(acc, v1);
        acc8_add(acc, v2); acc8_add(acc, v3);
    }
    for (; i < lim; ++i) {
        int s = bk[i] & MASK31;
        acc8_add(acc, A[(size_t)s * 16 + j8]);
    }
    if (cnt > BK_CAP) {               // ~1e-6 probability path
        int e = head_ov[n];
        while (e >= 0) {
            int s = ov_pay[e] & MASK31;
            acc8_add(acc, A[(size_t)s * 16 + j8]);
            e = ov_nxt[e];
        }
    }
    float inr = onrm_of(cnt);
    float onr = onrm_of(deg_out[n]);
    const float* bg = b_g0 + j8 * 8;
    float r[8];
#pragma unroll
    for (int k = 0; k < 8; ++k)
        r[k] = fmaxf(acc[k] * inr + bg[k], 0.f) * onr;
    uint4 o;
    o.x = pack2(r[0], r[1]); o.y = pack2(r[2], r[3]);
    o.z = pack2(r[4], r[5]); o.w = pack2(r[6], r[7]);
    B[(size_t)n * 16 + j8] = o;
}

// ---------------------------------------------------------------------------
// K4: fused layer-1 gather (bucket, unroll-2) + MFMA GEMM.
// ---------------------------------------------------------------------------
__global__ __launch_bounds__(256) void gemm1_fused_kernel(
    const unsigned short* __restrict__ Bbf,
    const int* __restrict__ bucket, const int* __restrict__ cnt_in,
    const int* __restrict__ head_ov, const int* __restrict__ ov_pay,
    const int* __restrict__ ov_nxt,
    const unsigned short* __restrict__ Wp, const float* __restrict__ bias,
    unsigned short* __restrict__ outbf)
{
    const int lane = threadIdx.x & 63;
    const int wave = threadIdx.x >> 6;
    const int m = lane & 15, q = lane >> 4;
    const int rbase = blockIdx.x * 64 + wave * 16;
    const int node = rbase + m;

    float ga[32];
#pragma unroll
    for (int i = 0; i < 32; ++i) ga[i] = 0.f;

    if (node < N_NODES) {
        const int cnt = cnt_in[node];
        const int* bk = bucket + (size_t)node * BK_CAP;
        int lim = min(cnt, BK_CAP);
        int i = 0;
        for (; i + 2 <= lim; i += 2) {
            int s0 = bk[i] & MASK31, s1 = bk[i + 1] & MASK31;
            const uint4* r0 = (const uint4*)(Bbf + (size_t)s0 * 128);
            const uint4* r1 = (const uint4*)(Bbf + (size_t)s1 * 128);
            uint4 a0 = r0[0 * 4 + q], a1 = r0[1 * 4 + q], a2 = r0[2 * 4 + q], a3 = r0[3 * 4 + q];
            uint4 c0 = r1[0 * 4 + q], c1 = r1[1 * 4 + q], c2 = r1[2 * 4 + q], c3 = r1[3 * 4 + q];
            acc8_add(ga +  0, a0); acc8_add(ga +  8, a1);
            acc8_add(ga + 16, a2); acc8_add(ga + 24, a3);
            acc8_add(ga +  0, c0); acc8_add(ga +  8, c1);
            acc8_add(ga + 16, c2); acc8_add(ga + 24, c3);
        }
        for (; i < lim; ++i) {
            int s = bk[i] & MASK31;
            const uint4* rp = (const uint4*)(Bbf + (size_t)s * 128);
#pragma unroll
            for (int kt = 0; kt < 4; ++kt) acc8_add(ga + kt * 8, rp[kt * 4 + q]);
        }
        if (cnt > BK_CAP) {
            int e = head_ov[node];
            while (e >= 0) {
                int s = ov_pay[e] & MASK31;
                const uint4* rp = (const uint4*)(Bbf + (size_t)s * 128);
#pragma unroll
                for (int kt = 0; kt < 4; ++kt) acc8_add(ga + kt * 8, rp[kt * 4 + q]);
                e = ov_nxt[e];
            }
        }
    }

    bfrag afr[4];
#pragma unroll
    for (int kt = 0; kt < 4; ++kt)
#pragma unroll
        for (int j = 0; j < 8; ++j)
            afr[kt][j] = (short)f2bf(ga[kt * 8 + j]);

    ffrag acc[8];
#pragma unroll
    for (int n0 = 0; n0 < 8; ++n0)
#pragma unroll
        for (int t = 0; t < 4; ++t) acc[n0][t] = 0.f;

#pragma unroll
    for (int n0 = 0; n0 < 8; ++n0)
#pragma unroll
        for (int kt = 0; kt < 4; ++kt) {
            bfrag bfr = *(const bfrag*)(Wp + ((size_t)(n0 * 4 + kt) * 64 + lane) * 8);
            acc[n0] = __builtin_amdgcn_mfma_f32_16x16x32_bf16(afr[kt], bfr, acc[n0], 0, 0, 0);
        }

    float ir[4];
#pragma unroll
    for (int r = 0; r < 4; ++r) {
        int orow = rbase + q * 4 + r;
        ir[r] = (orow < N_NODES) ? onrm_of(cnt_in[orow]) : 0.f;
    }
#pragma unroll
    for (int n0 = 0; n0 < 8; ++n0) {
        const int col = n0 * 16 + m;
        const float bj = bias[col];
#pragma unroll
        for (int r = 0; r < 4; ++r) {
            int orow = rbase + q * 4 + r;
            if (orow < N_NODES)
                outbf[(size_t)orow * 128 + col] = f2bf(fmaxf(acc[n0][r] * ir[r] + bj, 0.f));
        }
    }
}

// ---------------------------------------------------------------------------
// K5: final edge-typed gather (buckets, unroll-4) -> fp32 out.
// ---------------------------------------------------------------------------
__global__ __launch_bounds__(256) void final_kernel(
    const uint4* __restrict__ H,
    const int* __restrict__ bucket, const int* __restrict__ cnt_in,
    const int* __restrict__ head_ov, const int* __restrict__ ov_pay,
    const int* __restrict__ ov_nxt,
    const int* __restrict__ bucketB, const int* __restrict__ cntB,
    const int* __restrict__ head_ovB, const int* __restrict__ ovB_pay,
    const int* __restrict__ ovB_nxt,
    float4* __restrict__ out4) {
    int idx = blockIdx.x * blockDim.x + threadIdx.x;
    int n = idx >> 4, j8 = idx & 15;
    float acc[8] = {0.f, 0.f, 0.f, 0.f, 0.f, 0.f, 0.f, 0.f};
    const int cnt = cnt_in[n];
    const int* bk = bucket + (size_t)n * BK_CAP;
    int lim = min(cnt, BK_CAP);
    int i = 0;
    for (; i + 4 <= lim; i += 4) {
        int c0 = bk[i], c1 = bk[i + 1], c2 = bk[i + 2], c3 = bk[i + 3];
        uint4 v0 = H[(size_t)(c0 & MASK31) * 16 + j8];
        uint4 v1 = H[(size_t)(c1 & MASK31) * 16 + j8];
        uint4 v2 = H[(size_t)(c2 & MASK31) * 16 + j8];
        uint4 v3 = H[(size_t)(c3 & MASK31) * 16 + j8];
        acc8_addw(acc, v0, (c0 < 0) ? 2.0f : 1.0f);
        acc8_addw(acc, v1, (c1 < 0) ? 2.0f : 1.0f);
        acc8_addw(acc, v2, (c2 < 0) ? 2.0f : 1.0f);
        acc8_addw(acc, v3, (c3 < 0) ? 2.0f : 1.0f);
    }
    for (; i < lim; ++i) {
        int c = bk[i];
        acc8_addw(acc, H[(size_t)(c & MASK31) * 16 + j8], (c < 0) ? 2.0f : 1.0f);
    }
    if (cnt > BK_CAP) {
        int e = head_ov[n];
        while (e >= 0) {
            int c = ov_pay[e];
            acc8_addw(acc, H[(size_t)(c & MASK31) * 16 + j8], (c < 0) ? 2.0f : 1.0f);
            e = ov_nxt[e];
        }
    }
    const int cb = cntB[n];
    const int* bkB = bucketB + (size_t)n * BKB_CAP;
    int limB = min(cb, BKB_CAP);
    for (int k = 0; k < limB; ++k) {
        int d = bkB[k];
        acc8_add(acc, H[(size_t)d * 16 + j8]);
    }
    if (cb > BKB_CAP) {
        int e = head_ovB[n];
        while (e >= 0) {
            acc8_add(acc, H[(size_t)ovB_pay[e] * 16 + j8]);
            e = ovB_nxt[e];
        }
    }
    float4 o0 = {acc[0], acc[1], acc[2], acc[3]};
    float4 o1 = {acc[4], acc[5], acc[6], acc[7]};
    out4[(size_t)n * 32 + j8 * 2]     = o0;
    out4[(size_t)n * 32 + j8 * 2 + 1] = o1;
}

extern "C" void kernel_launch(void* const* d_in, const int* in_sizes, int n_in,
                              void* d_out, int out_size, void* d_ws, size_t ws_size,
                              hipStream_t stream) {
    const float* feat[4]  = {(const float*)d_in[0], (const float*)d_in[3],
                             (const float*)d_in[6], (const float*)d_in[9]};
    const float* W_fc[4]  = {(const float*)d_in[1], (const float*)d_in[4],
                             (const float*)d_in[7], (const float*)d_in[10]};
    const float* b_fc[4]  = {(const float*)d_in[2], (const float*)d_in[5],
                             (const float*)d_in[8], (const float*)d_in[11]};
    const int*   src      = (const int*)d_in[12];
    const int*   dst      = (const int*)d_in[13];
    const int*   efeat    = (const int*)d_in[14];
    const float* b_g0     = (const float*)d_in[15];
    const float* W_g1     = (const float*)d_in[16];
    const float* b_g1     = (const float*)d_in[17];
    float* out = (float*)d_out;

    // ---- workspace layout (16B blocks first), ~44 MB ----
    char* p = (char*)d_ws;
    unsigned short* Abf = (unsigned short*)p; p += (size_t)N_NODES * HDIM * 2;  // 12.8 MB
    unsigned short* Bbf = (unsigned short*)p; p += (size_t)N_NODES * HDIM * 2;  // 12.8 MB
    unsigned short* Wp  = (unsigned short*)p; p += (size_t)65536 * 2;           // 128 KB
    int* bucket  = (int*)p; p += (size_t)N_NODES * BK_CAP * 4;   // 6.4 MB
    int* bucketB = (int*)p; p += (size_t)N_NODES * BKB_CAP * 4;  // 1.6 MB
    int* ov_pay  = (int*)p; p += (size_t)E_EDGES * 4;            // 2.4 MB
    int* ov_nxt  = (int*)p; p += (size_t)E_EDGES * 4;            // 2.4 MB
    int* ovB_pay = (int*)p; p += (size_t)E_EDGES * 4;            // 2.4 MB
    int* ovB_nxt = (int*)p; p += (size_t)E_EDGES * 4;            // 2.4 MB
    // init region (contiguous): head_ov=-1, head_ovB=-1, cnt_in=0, cntB=0, deg_out=0
    int* head_ov  = (int*)p; p += (size_t)N_NODES * 4;
    int* head_ovB = (int*)p; p += (size_t)N_NODES * 4;
    int* cnt_in   = (int*)p; p += (size_t)N_NODES * 4;
    int* cntB     = (int*)p; p += (size_t)N_NODES * 4;
    int* deg_out  = (int*)p; p += (size_t)N_NODES * 4;

    const unsigned short* Wpg = Wp + 49152;

    // K0: weight packing + init (250k ints)
    prep_kernel<<<32 + (5 * N_NODES + 1023) / 1024, 256, 0, stream>>>(
        W_fc[0], W_fc[1], W_fc[2], W_fc[3], W_g1, Wp, head_ov);

    // K1: bucket build (atomics) + 4 FC GEMMs (MFMA), overlapped
    mega_kernel<<<NBLK_BUILD + 4 * NBLK_FC, 256, 0, stream>>>(
        src, dst, efeat, cnt_in, cntB, deg_out,
        bucket, bucketB, head_ov, ov_pay, ov_nxt, head_ovB, ovB_pay, ovB_nxt,
        feat[0], feat[1], feat[2], feat[3], Wp,
        b_fc[0], b_fc[1], b_fc[2], b_fc[3], Abf);

    const int grid_node = (N_NODES * 16) / 256;   // 3125 exact

    // K2: A *= onrm(deg_out)  (coalesced)
    scale_kernel<<<grid_node, 256, 0, stream>>>((uint4*)Abf, deg_out);

    // K3: layer0 bucket gather
    agg0_kernel<<<grid_node, 256, 0, stream>>>(
        (const uint4*)Abf, bucket, cnt_in, head_ov, ov_pay, ov_nxt,
        deg_out, b_g0, (uint4*)Bbf);

    // K4: fused layer1 bucket gather + GEMM
    gemm1_fused_kernel<<<(N_NODES + 63) / 64, 256, 0, stream>>>(
        Bbf, bucket, cnt_in, head_ov, ov_pay, ov_nxt, Wpg, b_g1, Abf);

    // K5: final edge-typed bucket gather into fp32 d_out
    final_kernel<<<grid_node, 256, 0, stream>>>(
        (const uint4*)Abf, bucket, cnt_in, head_ov, ov_pay, ov_nxt,
        bucketB, cntB, head_ovB, ovB_pay, ovB_nxt, (float4*)out);
}